// Round 4
// baseline (85.136 us; speedup 1.0000x reference)
//
#include <hip/hip_runtime.h>
#include <string.h>

#define AA (-0.75f)

__device__ __forceinline__ float k1f(float x) {
    return ((AA + 2.0f) * x - (AA + 3.0f)) * x * x + 1.0f;
}
__device__ __forceinline__ float k2f(float x) {
    return ((AA * x - 5.0f * AA) * x + 8.0f * AA) * x - 4.0f * AA;
}

__device__ __forceinline__ int reflect_clip(int idx, int size) {
    int span = size - 1;
    int i = idx < 0 ? -idx : idx;
    i = i % (2 * span);
    if (i > span) i = 2 * span - i;
    return i;
}

// LDS bank swizzle: logical element a -> a ^ ((a>>5)&31). Bijective per row.
__device__ __forceinline__ int swz(int a) { return a ^ ((a >> 5) & 31); }

// Separable bicubic, 4 output rows per block, double-buffered LDS pipeline.
// Per row: issue next row's 16 float4 loads (regs, full MLP) -> phase2 gather
// from LDS (hides load latency) -> vertical combine -> write other buffer.
__global__ __launch_bounds__(256, 4)
void pds4_kernel(const float* __restrict__ x,
                 const float* __restrict__ rate,
                 const float* __restrict__ center,
                 float* __restrict__ out)
{
    constexpr int C = 8, H = 512, W = 512, ROWS = 4;

    // XCD-chunked remap: 2048 blocks, 2048 % 8 == 0 -> bijective; each XCD
    // owns contiguous (b, hgroup) ranges -> input-row L2 locality.
    const int orig = blockIdx.x;
    const int id = (orig & 7) * 256 + (orig >> 3);
    const int b  = id >> 7;          // 16 batches
    const int h0 = (id & 127) * ROWS;

    const float r  = rate[b];
    const float cx = center[2 * b + 0];
    const float cy = center[2 * b + 1];
    const int t = threadIdx.x;

    // ---- x taps, once per block (cols 2t, 2t+1) ----
    int   sA0, sA1, sA2, sA3, sB0, sB1, sB2, sB3;
    float wxA0, wxA1, wxA2, wxA3, wxB0, wxB1, wxB2, wxB3;
    {
        const int w = 2 * t;
        const float gx = 0.00390625f * (float)w - 1.0f;
        const float Gx = (gx - cx) / r + cx;
        const float ix = (Gx + 1.0f) * 0.5f * 511.0f;
        const float x0 = floorf(ix);
        const float tx = ix - x0;
        const int x0i = (int)x0;
        wxA0 = k2f(tx + 1.0f); wxA1 = k1f(tx);
        wxA2 = k1f(1.0f - tx); wxA3 = k2f(2.0f - tx);
        sA0 = swz(reflect_clip(x0i - 1, W)); sA1 = swz(reflect_clip(x0i,     W));
        sA2 = swz(reflect_clip(x0i + 1, W)); sA3 = swz(reflect_clip(x0i + 2, W));
    }
    {
        const int w = 2 * t + 1;
        const float gx = 0.00390625f * (float)w - 1.0f;
        const float Gx = (gx - cx) / r + cx;
        const float ix = (Gx + 1.0f) * 0.5f * 511.0f;
        const float x0 = floorf(ix);
        const float tx = ix - x0;
        const int x0i = (int)x0;
        wxB0 = k2f(tx + 1.0f); wxB1 = k1f(tx);
        wxB2 = k1f(1.0f - tx); wxB3 = k2f(2.0f - tx);
        sB0 = swz(reflect_clip(x0i - 1, W)); sB1 = swz(reflect_clip(x0i,     W));
        sB2 = swz(reflect_clip(x0i + 1, W)); sB3 = swz(reflect_clip(x0i + 2, W));
    }

    __shared__ float buf[2][C][W];       // 32 KiB double buffer (swizzled rows)

    const float* imgb = x + (size_t)b * C * H * W;

    // per-iteration k: lane -> (channel, 16B group)
    int cch[4], cc4[4];
    #pragma unroll
    for (int k = 0; k < 4; ++k) {
        const int g = t + k * 256;
        cch[k] = g >> 7;
        cc4[k] = (g & 127) << 2;
    }

    float4 pf[4][4];                      // prefetch regs: [k][row-tap]
    float  wyN0, wyN1, wyN2, wyN3;        // y weights for prefetched row

    // ---- helpers as macros (keep static indexing) ----
#define YTAPS(hh, w0, w1, w2, w3, r0, r1, r2, r3)                         \
    {                                                                      \
        const float gy = 0.00390625f * (float)(hh) - 1.0f;                 \
        const float Gy = (gy - cy) / r + cy;                               \
        const float iy = (Gy + 1.0f) * 0.5f * 511.0f;                      \
        const float y0 = floorf(iy);                                       \
        const float ty = iy - y0;                                          \
        const int   y0i = (int)y0;                                         \
        w0 = k2f(ty + 1.0f); w1 = k1f(ty);                                 \
        w2 = k1f(1.0f - ty); w3 = k2f(2.0f - ty);                          \
        r0 = (size_t)reflect_clip(y0i - 1, H) * W;                         \
        r1 = (size_t)reflect_clip(y0i    , H) * W;                         \
        r2 = (size_t)reflect_clip(y0i + 1, H) * W;                         \
        r3 = (size_t)reflect_clip(y0i + 2, H) * W;                         \
    }

#define ISSUE(r0, r1, r2, r3)                                              \
    _Pragma("unroll")                                                      \
    for (int k = 0; k < 4; ++k) {                                          \
        const float* img = imgb + (size_t)cch[k] * (H * W);                \
        pf[k][0] = *(const float4*)(img + (r0) + cc4[k]);                  \
        pf[k][1] = *(const float4*)(img + (r1) + cc4[k]);                  \
        pf[k][2] = *(const float4*)(img + (r2) + cc4[k]);                  \
        pf[k][3] = *(const float4*)(img + (r3) + cc4[k]);                  \
    }

#define COMBINE(dstbuf, w0, w1, w2, w3)                                    \
    _Pragma("unroll")                                                      \
    for (int k = 0; k < 4; ++k) {                                          \
        const float4 a0 = pf[k][0], a1 = pf[k][1],                         \
                     a2 = pf[k][2], a3 = pf[k][3];                         \
        float e0 = w0 * a0.x + w1 * a1.x + w2 * a2.x + w3 * a3.x;          \
        float e1 = w0 * a0.y + w1 * a1.y + w2 * a2.y + w3 * a3.y;          \
        float e2 = w0 * a0.z + w1 * a1.z + w2 * a2.z + w3 * a3.z;          \
        float e3 = w0 * a0.w + w1 * a1.w + w2 * a2.w + w3 * a3.w;          \
        const int c4   = cc4[k];                                           \
        const int v    = (c4 >> 5) & 31;                                   \
        const int base = c4 ^ (v & ~3);                                    \
        const int p    = v & 3;                                            \
        const bool q1 = (p & 1) != 0;                                      \
        const bool q2 = (p & 2) != 0;                                      \
        float t0 = q1 ? e1 : e0;                                           \
        float t1 = q1 ? e0 : e1;                                           \
        float t2 = q1 ? e3 : e2;                                           \
        float t3 = q1 ? e2 : e3;                                           \
        float u0 = q2 ? t2 : t0;                                           \
        float u1 = q2 ? t3 : t1;                                           \
        float u2 = q2 ? t0 : t2;                                           \
        float u3 = q2 ? t1 : t3;                                           \
        *(float4*)&(dstbuf)[cch[k]][base] = make_float4(u0, u1, u2, u3);   \
    }

    // ---- prologue: row h0 into buf[0] ----
    {
        size_t ro0, ro1, ro2, ro3;
        YTAPS(h0, wyN0, wyN1, wyN2, wyN3, ro0, ro1, ro2, ro3);
        ISSUE(ro0, ro1, ro2, ro3);
        COMBINE(buf[0], wyN0, wyN1, wyN2, wyN3);
    }
    __syncthreads();

    // ---- pipelined rows ----
    #pragma unroll
    for (int j = 0; j < ROWS; ++j) {
        const int h = h0 + j;

        if (j < ROWS - 1) {                         // issue next row's loads
            size_t ro0, ro1, ro2, ro3;
            YTAPS(h + 1, wyN0, wyN1, wyN2, wyN3, ro0, ro1, ro2, ro3);
            ISSUE(ro0, ro1, ro2, ro3);
        }

        // phase 2: horizontal gather from buf[j&1], nontemporal float2 stores
        {
            const float* trow0 = &buf[j & 1][0][0];
            float* obase = out + ((size_t)b * C * H + h) * W + 2 * t;
            #pragma unroll
            for (int c = 0; c < C; ++c) {
                const float* tr = trow0 + c * W;
                const float s0 = wxA0 * tr[sA0] + wxA1 * tr[sA1]
                               + wxA2 * tr[sA2] + wxA3 * tr[sA3];
                const float s1 = wxB0 * tr[sB0] + wxB1 * tr[sB1]
                               + wxB2 * tr[sB2] + wxB3 * tr[sB3];
                float2 v2 = make_float2(s0, s1);
                double dv;
                memcpy(&dv, &v2, 8);
                __builtin_nontemporal_store(dv, (double*)(obase + (size_t)c * (H * W)));
            }
        }

        if (j < ROWS - 1) {                         // combine + write other buf
            COMBINE(buf[(j + 1) & 1], wyN0, wyN1, wyN2, wyN3);
            __syncthreads();
        }
    }
#undef YTAPS
#undef ISSUE
#undef COMBINE
}

extern "C" void kernel_launch(void* const* d_in, const int* in_sizes, int n_in,
                              void* d_out, int out_size, void* d_ws, size_t ws_size,
                              hipStream_t stream) {
    const float* x      = (const float*)d_in[0];
    const float* rate   = (const float*)d_in[1];
    const float* center = (const float*)d_in[2];
    float* out          = (float*)d_out;

    constexpr int B = 16, H = 512, ROWS = 4;
    dim3 grid(B * (H / ROWS));
    dim3 block(256);
    pds4_kernel<<<grid, block, 0, stream>>>(x, rate, center, out);
}

// Round 5
// 56.839 us; speedup vs baseline: 1.4979x; 1.4979x over previous
//
#include <hip/hip_runtime.h>
#include <string.h>

#define AA (-0.75f)

__device__ __forceinline__ float k1f(float x) {
    return ((AA + 2.0f) * x - (AA + 3.0f)) * x * x + 1.0f;
}
__device__ __forceinline__ float k2f(float x) {
    return ((AA * x - 5.0f * AA) * x + 8.0f * AA) * x - 4.0f * AA;
}

__device__ __forceinline__ int reflect_clip(int idx, int size) {
    int span = size - 1;
    int i = idx < 0 ? -idx : idx;
    i = i % (2 * span);
    if (i > span) i = 2 * span - i;
    return i;
}

// LDS bank swizzle: logical element a -> a ^ ((a>>5)&31). Bijective per row.
__device__ __forceinline__ int swz(int a) { return a ^ ((a >> 5) & 31); }

// Separable bicubic, one block per (b,h), 256 threads.
// Order tuned for latency overlap: y-taps (short) -> issue ALL 16 float4
// loads (pinned) -> x-tap VALU chain overlaps load flight -> combine -> LDS
// -> horizontal 4-tap gather, nontemporal float2 stores.
__global__ __launch_bounds__(256, 4)
void pds5_kernel(const float* __restrict__ x,
                 const float* __restrict__ rate,
                 const float* __restrict__ center,
                 float* __restrict__ out)
{
    constexpr int C = 8, H = 512, W = 512;

    // XCD-chunked remap (8192 % 8 == 0 -> bijective): h-neighbors share tap
    // rows -> same-XCD L2 locality.
    const int orig = blockIdx.x;
    const int id = (orig & 7) * 1024 + (orig >> 3);
    const int b = id >> 9;
    const int h = id & (H - 1);

    const float r  = rate[b];
    const float cx = center[2 * b + 0];
    const float cy = center[2 * b + 1];
    const float inv_r = 1.0f / r;
    const int t = threadIdx.x;

    // ---- y taps (block-uniform, short chain) ----
    const float gy = 0.00390625f * (float)h - 1.0f;
    const float Gy = (gy - cy) * inv_r + cy;
    const float iy = (Gy + 1.0f) * 0.5f * 511.0f;
    const float y0 = floorf(iy);
    const float ty = iy - y0;
    const int   y0i = (int)y0;
    const float wy0 = k2f(ty + 1.0f);
    const float wy1 = k1f(ty);
    const float wy2 = k1f(1.0f - ty);
    const float wy3 = k2f(2.0f - ty);
    const int ro0 = reflect_clip(y0i - 1, H) * W;
    const int ro1 = reflect_clip(y0i    , H) * W;
    const int ro2 = reflect_clip(y0i + 1, H) * W;
    const int ro3 = reflect_clip(y0i + 2, H) * W;

    // ---- issue ALL 16 phase-1 loads (4 channel-groups x 4 row-taps) ----
    const float* imgb = x + (size_t)b * C * H * W;
    const int cc4 = (t & 127) << 2;           // 16B-aligned group in row
    const int ch0 = (t >> 7);                 // 0 or 1
    const float* base0 = imgb + (size_t)(ch0 + 0) * (H * W) + cc4;
    const float* base1 = imgb + (size_t)(ch0 + 2) * (H * W) + cc4;
    const float* base2 = imgb + (size_t)(ch0 + 4) * (H * W) + cc4;
    const float* base3 = imgb + (size_t)(ch0 + 6) * (H * W) + cc4;

    float4 p00 = *(const float4*)(base0 + ro0);
    float4 p01 = *(const float4*)(base0 + ro1);
    float4 p02 = *(const float4*)(base0 + ro2);
    float4 p03 = *(const float4*)(base0 + ro3);
    float4 p10 = *(const float4*)(base1 + ro0);
    float4 p11 = *(const float4*)(base1 + ro1);
    float4 p12 = *(const float4*)(base1 + ro2);
    float4 p13 = *(const float4*)(base1 + ro3);
    float4 p20 = *(const float4*)(base2 + ro0);
    float4 p21 = *(const float4*)(base2 + ro1);
    float4 p22 = *(const float4*)(base2 + ro2);
    float4 p23 = *(const float4*)(base2 + ro3);
    float4 p30 = *(const float4*)(base3 + ro0);
    float4 p31 = *(const float4*)(base3 + ro1);
    float4 p32 = *(const float4*)(base3 + ro2);
    float4 p33 = *(const float4*)(base3 + ro3);
    // Pin the loads above this point (memory clobber: loads may not sink).
    asm volatile("" ::: "memory");

    // ---- x taps for cols 2t, 2t+1 (VALU, overlaps load flight) ----
    int   sA0, sA1, sA2, sA3, sB0, sB1, sB2, sB3;
    float wxA0, wxA1, wxA2, wxA3, wxB0, wxB1, wxB2, wxB3;
    {
        const int w = 2 * t;
        const float gx = 0.00390625f * (float)w - 1.0f;
        const float Gx = (gx - cx) * inv_r + cx;
        const float ix = (Gx + 1.0f) * 0.5f * 511.0f;
        const float x0 = floorf(ix);
        const float tx = ix - x0;
        const int x0i = (int)x0;
        wxA0 = k2f(tx + 1.0f); wxA1 = k1f(tx);
        wxA2 = k1f(1.0f - tx); wxA3 = k2f(2.0f - tx);
        sA0 = swz(reflect_clip(x0i - 1, W)); sA1 = swz(reflect_clip(x0i,     W));
        sA2 = swz(reflect_clip(x0i + 1, W)); sA3 = swz(reflect_clip(x0i + 2, W));
    }
    {
        const int w = 2 * t + 1;
        const float gx = 0.00390625f * (float)w - 1.0f;
        const float Gx = (gx - cx) * inv_r + cx;
        const float ix = (Gx + 1.0f) * 0.5f * 511.0f;
        const float x0 = floorf(ix);
        const float tx = ix - x0;
        const int x0i = (int)x0;
        wxB0 = k2f(tx + 1.0f); wxB1 = k1f(tx);
        wxB2 = k1f(1.0f - tx); wxB3 = k2f(2.0f - tx);
        sB0 = swz(reflect_clip(x0i - 1, W)); sB1 = swz(reflect_clip(x0i,     W));
        sB2 = swz(reflect_clip(x0i + 1, W)); sB3 = swz(reflect_clip(x0i + 2, W));
    }

    __shared__ float tmp[C][W];   // 16 KiB, swizzled rows

    // ---- vertical combine -> swizzled LDS ----
    {
        const int v    = (cc4 >> 5) & 31;
        const int base = cc4 ^ (v & ~3);
        const int p    = v & 3;
        const bool q1 = (p & 1) != 0;
        const bool q2 = (p & 2) != 0;
#define COMB1(cc, a0, a1, a2, a3)                                          \
        {                                                                  \
            float e0 = wy0 * a0.x + wy1 * a1.x + wy2 * a2.x + wy3 * a3.x;  \
            float e1 = wy0 * a0.y + wy1 * a1.y + wy2 * a2.y + wy3 * a3.y;  \
            float e2 = wy0 * a0.z + wy1 * a1.z + wy2 * a2.z + wy3 * a3.z;  \
            float e3 = wy0 * a0.w + wy1 * a1.w + wy2 * a2.w + wy3 * a3.w;  \
            float t0 = q1 ? e1 : e0;                                       \
            float t1 = q1 ? e0 : e1;                                       \
            float t2 = q1 ? e3 : e2;                                       \
            float t3 = q1 ? e2 : e3;                                       \
            float u0 = q2 ? t2 : t0;                                       \
            float u1 = q2 ? t3 : t1;                                       \
            float u2 = q2 ? t0 : t2;                                       \
            float u3 = q2 ? t1 : t3;                                       \
            *(float4*)&tmp[cc][base] = make_float4(u0, u1, u2, u3);        \
        }
        COMB1(ch0 + 0, p00, p01, p02, p03);
        COMB1(ch0 + 2, p10, p11, p12, p13);
        COMB1(ch0 + 4, p20, p21, p22, p23);
        COMB1(ch0 + 6, p30, p31, p32, p33);
#undef COMB1
    }
    __syncthreads();

    // ---- horizontal pass: 4 LDS taps per output, NT float2 stores ----
    float* obase = out + ((size_t)b * C * H + h) * W + 2 * t;
    #pragma unroll
    for (int c = 0; c < C; ++c) {
        const float* tr = tmp[c];
        const float s0 = wxA0 * tr[sA0] + wxA1 * tr[sA1]
                       + wxA2 * tr[sA2] + wxA3 * tr[sA3];
        const float s1 = wxB0 * tr[sB0] + wxB1 * tr[sB1]
                       + wxB2 * tr[sB2] + wxB3 * tr[sB3];
        float2 v2 = make_float2(s0, s1);
        double dv;
        memcpy(&dv, &v2, 8);
        __builtin_nontemporal_store(dv, (double*)(obase + (size_t)c * (H * W)));
    }
}

extern "C" void kernel_launch(void* const* d_in, const int* in_sizes, int n_in,
                              void* d_out, int out_size, void* d_ws, size_t ws_size,
                              hipStream_t stream) {
    const float* x      = (const float*)d_in[0];
    const float* rate   = (const float*)d_in[1];
    const float* center = (const float*)d_in[2];
    float* out          = (float*)d_out;

    constexpr int B = 16, H = 512;
    dim3 grid(B * H);
    dim3 block(256);
    pds5_kernel<<<grid, block, 0, stream>>>(x, rate, center, out);
}